// Round 5
// baseline (372.514 us; speedup 1.0000x reference)
//
#include <hip/hip_runtime.h>

#define S_LEN  2048
#define NH     16
#define HD     64
#define DMODEL 1024

using bf16x8 = __attribute__((ext_vector_type(8))) __bf16;
using f32x4  = __attribute__((ext_vector_type(4))) float;

__device__ __forceinline__ unsigned short f2bf(float f) {
    unsigned u = __float_as_uint(f);
    u += 0x7FFFu + ((u >> 16) & 1u);   // RNE
    return (unsigned short)(u >> 16);
}
// pack trunc(a)->lo, trunc(b)->hi in one v_perm
__device__ __forceinline__ unsigned pk_trunc(float lo, float hi) {
    return __builtin_amdgcn_perm(__float_as_uint(hi), __float_as_uint(lo), 0x07060302u);
}

// async global->LDS, 16B per lane; dest = wave-uniform base + lane*16
#define GLDS16(gsrc, ldst) \
    __builtin_amdgcn_global_load_lds((__attribute__((address_space(1))) void*)(gsrc), \
                                     (__attribute__((address_space(3))) void*)(ldst), 16, 0, 0)

#define WAIT_LGKM0() __builtin_amdgcn_s_waitcnt(0xC07F)   // lgkmcnt(0) only

// ---------------------------------------------------------------------------
// Fused prep: x fp32->bf16 (blocks 0..4095), weight transpose+convert
// (blocks 4096..8191), merge-flag zeroing (block 0).
// ---------------------------------------------------------------------------
__global__ __launch_bounds__(256) void prep_kernel(
    const float* __restrict__ x, const float* __restrict__ w_qkv,
    const float* __restrict__ w_out,
    unsigned short* __restrict__ xb, unsigned short* __restrict__ wqkvT,
    unsigned short* __restrict__ woutT, int* __restrict__ flags) {
    __shared__ float T[32][33];
    int bx = blockIdx.x;
    if (bx < 4096) {
        int idx = (bx * 256 + threadIdx.x) * 4;
        float4 v = *(const float4*)(x + idx);
        ushort4 o;
        o.x = f2bf(v.x); o.y = f2bf(v.y); o.z = f2bf(v.z); o.w = f2bf(v.w);
        *(ushort4*)(xb + idx) = o;
        if (bx == 0)
            for (int i = threadIdx.x; i < 480; i += 256) flags[i] = 0;
        return;
    }
    int tb = bx - 4096;
    int tcol = tb & 127, krow = tb >> 7;
    const float* in;
    unsigned short* out;
    int N, nbx;
    if (tcol < 96) { in = w_qkv; out = wqkvT; N = 3072; nbx = tcol; }
    else           { in = w_out; out = woutT; N = 1024; nbx = tcol - 96; }
    int r  = threadIdx.x >> 3;
    int c4 = (threadIdx.x & 7) * 4;
    int kbase = krow * 32, nbase = nbx * 32;
    float4 v = *(const float4*)(in + (size_t)(kbase + r) * N + nbase + c4);
    T[r][c4 + 0] = v.x; T[r][c4 + 1] = v.y; T[r][c4 + 2] = v.z; T[r][c4 + 3] = v.w;
    __syncthreads();
    ushort4 o;
    o.x = f2bf(T[c4 + 0][r]); o.y = f2bf(T[c4 + 1][r]);
    o.z = f2bf(T[c4 + 2][r]); o.w = f2bf(T[c4 + 3][r]);
    *(ushort4*)(out + (size_t)(nbase + r) * 1024 + kbase + c4) = o;
}

// ---------------------------------------------------------------------------
// MFMA NT GEMM mainloop, BK=64: halves barrier pairs vs BK=32.
// A[M,K], B[N,K] bf16 k-contiguous. LDS 2x16KB, 8-chunk/row XOR swizzle.
// 4 waves, each a 64x64 sub-tile: 4x4x(2 k-halves) = 32 MFMA per stage.
// ---------------------------------------------------------------------------
__device__ __forceinline__ void mfma_mainloop64(const unsigned short* __restrict__ A,
                                                const unsigned short* __restrict__ B,
                                                int K, int m0, int n0,
                                                unsigned short* As, unsigned short* Bs,
                                                f32x4 acc[4][4]) {
    const int lane = threadIdx.x & 63, wave = threadIdx.x >> 6;
    const int quad = lane >> 4, l15 = lane & 15;
    const int wm0 = (wave >> 1) * 64, wn0 = (wave & 1) * 64;

    for (int k0 = 0; k0 < K; k0 += 64) {
        __syncthreads();
        #pragma unroll
        for (int j = 0; j < 8; ++j) {
            int c0 = (j & 3) * 256 + wave * 64;   // chunk base, wave-uniform
            int c  = c0 + lane;
            int r = c >> 3, pc = c & 7, q = pc ^ (r & 7);
            if (j < 4)
                GLDS16(A + (size_t)(m0 + r) * K + k0 + q * 8, As + c0 * 8);
            else
                GLDS16(B + (size_t)(n0 + r) * K + k0 + q * 8, Bs + c0 * 8);
        }
        __syncthreads();

        bf16x8 af[2][4], bfr[2][4];
        #pragma unroll
        for (int mi = 0; mi < 4; ++mi) {
            int r = wm0 + mi * 16 + l15, x = r & 7;
            af[0][mi] = *(const bf16x8*)(As + r * 64 + ((quad    ) ^ x) * 8);
            af[1][mi] = *(const bf16x8*)(As + r * 64 + ((4 + quad) ^ x) * 8);
        }
        #pragma unroll
        for (int ni = 0; ni < 4; ++ni) {
            int r = wn0 + ni * 16 + l15, x = r & 7;
            bfr[0][ni] = *(const bf16x8*)(Bs + r * 64 + ((quad    ) ^ x) * 8);
            bfr[1][ni] = *(const bf16x8*)(Bs + r * 64 + ((4 + quad) ^ x) * 8);
        }
        #pragma unroll
        for (int h = 0; h < 2; ++h)
            #pragma unroll
            for (int mi = 0; mi < 4; ++mi)
                #pragma unroll
                for (int ni = 0; ni < 4; ++ni)
                    acc[mi][ni] = __builtin_amdgcn_mfma_f32_16x16x32_bf16(
                        af[h][mi], bfr[h][ni], acc[mi][ni], 0, 0, 0);
    }
}

// ---------------------------------------------------------------------------
// GEMM1: qkv projection. LDS-transpose epilogue -> dwordx4 stores.
// Q -> Qt [bh][d][s] PRE-SCALED by 1/sqrt(64)*log2e, K -> Kh [bh][s][d],
// V -> Vt [bh][d][s].
// ---------------------------------------------------------------------------
__global__ __launch_bounds__(256) void gemm_qkv_kernel(
    const unsigned short* __restrict__ xb, const unsigned short* __restrict__ wT,
    const float* __restrict__ bias,
    unsigned short* __restrict__ Qt, unsigned short* __restrict__ Kh,
    unsigned short* __restrict__ Vt) {
    __shared__ __align__(16) unsigned short Sh[16384];  // As | Bs, reused by epilogue
    unsigned short* As = Sh;
    unsigned short* Bs = Sh + 8192;

    f32x4 acc[4][4];
    #pragma unroll
    for (int i = 0; i < 4; ++i)
        #pragma unroll
        for (int j = 0; j < 4; ++j) acc[i][j] = (f32x4){0.f, 0.f, 0.f, 0.f};

    int m0 = blockIdx.y * 128, n0 = blockIdx.x * 128;
    mfma_mainloop64(xb, wT, DMODEL, m0, n0, As, Bs, acc);

    const int lane = threadIdx.x & 63, wave = threadIdx.x >> 6;
    const int quad = lane >> 4, l15 = lane & 15;
    const int wm0 = (wave >> 1) * 64, wn0 = (wave & 1) * 64;

    const int colbase = n0 + wn0;            // 64-aligned -> uniform t,h per wave
    const int t = colbase >> 10;
    const int h = (colbase >> 6) & (NH - 1);
    const float qscale = (t == 0) ? 0.125f * 1.44269504088896f : 1.0f;
    float bv[4];
    #pragma unroll
    for (int ni = 0; ni < 4; ++ni) bv[ni] = bias[colbase + ni * 16 + l15];

    __syncthreads();                         // everyone done reading As/Bs
    unsigned short* Lw = Sh + wave * 1536;   // per-wave scratch (3 KB)

    #pragma unroll
    for (int mi = 0; mi < 4; ++mi) {
        int mbase = m0 + wm0 + mi * 16;
        int b = mbase >> 11, sbase = mbase & (S_LEN - 1);
        if (t == 1) {
            // K: want [s][d] rows; Lw[r*72 + c]
            #pragma unroll
            for (int ni = 0; ni < 4; ++ni)
                #pragma unroll
                for (int r = 0; r < 4; ++r)
                    Lw[(quad * 4 + r) * 72 + ni * 16 + l15] =
                        f2bf(acc[mi][ni][r] + bv[ni]);
            WAIT_LGKM0();
            int rr = lane & 15, dc = (lane >> 4) * 16;
            uint4 v0 = *(const uint4*)(Lw + rr * 72 + dc);
            uint4 v1 = *(const uint4*)(Lw + rr * 72 + dc + 8);
            unsigned short* dst =
                Kh + ((size_t)(b * NH + h) * S_LEN + sbase + rr) * HD + dc;
            *(uint4*)dst = v0;
            *(uint4*)(dst + 8) = v1;
        } else {
            // Q/V: want [d][s] rows; Lw[c*24 + r]
            #pragma unroll
            for (int ni = 0; ni < 4; ++ni)
                #pragma unroll
                for (int r = 0; r < 4; ++r)
                    Lw[(ni * 16 + l15) * 24 + quad * 4 + r] =
                        f2bf((acc[mi][ni][r] + bv[ni]) * qscale);
            WAIT_LGKM0();
            int c = lane;                    // d within head
            uint4 v0 = *(const uint4*)(Lw + c * 24);
            uint4 v1 = *(const uint4*)(Lw + c * 24 + 8);
            unsigned short* base = (t == 0) ? Qt : Vt;
            unsigned short* dst =
                base + ((size_t)(b * NH + h) * HD + c) * S_LEN + sbase;
            *(uint4*)dst = v0;
            *(uint4*)(dst + 8) = v1;
        }
        WAIT_LGKM0();                        // stores consumed Lw before next mi
    }
}

// ---------------------------------------------------------------------------
// GEMM3: out = zb @ w_outT + b_out, fp32 output
// ---------------------------------------------------------------------------
__global__ __launch_bounds__(256) void gemm_out_kernel(
    const unsigned short* __restrict__ zb, const unsigned short* __restrict__ wT,
    const float* __restrict__ bias, float* __restrict__ out) {
    __shared__ __align__(16) unsigned short As[8192], Bs[8192];
    f32x4 acc[4][4];
    #pragma unroll
    for (int i = 0; i < 4; ++i)
        #pragma unroll
        for (int j = 0; j < 4; ++j) acc[i][j] = (f32x4){0.f, 0.f, 0.f, 0.f};

    int m0 = blockIdx.y * 128, n0 = blockIdx.x * 128;
    mfma_mainloop64(zb, wT, DMODEL, m0, n0, As, Bs, acc);

    const int lane = threadIdx.x & 63, wave = threadIdx.x >> 6;
    const int quad = lane >> 4, l15 = lane & 15;
    const int wm0 = (wave >> 1) * 64, wn0 = (wave & 1) * 64;
    #pragma unroll
    for (int mi = 0; mi < 4; ++mi) {
        #pragma unroll
        for (int ni = 0; ni < 4; ++ni) {
            int col = n0 + wn0 + ni * 16 + l15;
            float bvv = bias[col];
            #pragma unroll
            for (int r = 0; r < 4; ++r)
                out[(size_t)(m0 + wm0 + mi * 16 + quad * 4 + r) * DMODEL + col] =
                    acc[mi][ni][r] + bvv;
        }
    }
}

// ---------------------------------------------------------------------------
// Balanced causal schedule: 47 entries {qt, kt_lo, kt_hi, part}, size-descending.
// ---------------------------------------------------------------------------
__device__ const int g_sched[47 * 4] = {
    16,0,16,-1,
    31,0,15,0,  31,16,31,1,  30,0,15,0,  15,0,15,-1,
    30,16,30,1, 29,0,14,0,   29,15,29,1, 28,0,14,0,  14,0,14,-1,
    28,15,28,1, 27,0,13,0,   27,14,27,1, 26,0,13,0,  13,0,13,-1,
    26,14,26,1, 25,0,12,0,   25,13,25,1, 24,0,12,0,  12,0,12,-1,
    24,13,24,1, 23,0,11,0,   23,12,23,1, 22,0,11,0,  11,0,11,-1,
    22,12,22,1, 21,0,10,0,   21,11,21,1, 20,0,10,0,  10,0,10,-1,
    20,11,20,1, 19,0,9,0,    19,10,19,1, 18,0,9,0,   9,0,9,-1,
    18,10,18,1, 17,0,8,0,    17,9,17,1,  8,0,8,-1,
    7,0,7,-1, 6,0,6,-1, 5,0,5,-1, 4,0,4,-1, 3,0,3,-1, 2,0,2,-1, 1,0,1,-1, 0,0,0,-1
};

// ---------------------------------------------------------------------------
// Flash attention, S^T orientation (S^T = K Q^T, Z^T = V^T P), fixed-max
// softmax, self-merging split-K partials (threadfence-reduction pattern).
// ---------------------------------------------------------------------------
__global__ __launch_bounds__(256) void attn_mfma_kernel(
    const unsigned short* __restrict__ Qt, const unsigned short* __restrict__ Kh,
    const unsigned short* __restrict__ Vt, unsigned short* __restrict__ zb,
    float* __restrict__ Zp, float* __restrict__ lp, int* __restrict__ flags) {
    __shared__ __align__(16) unsigned short Ks[64 * 64];    // [key][d], swizzled
    __shared__ __align__(16) unsigned short Vs[64 * 64];    // [d][key], swizzled
    __shared__ __align__(16) unsigned short Pl[4 * 16 * 64];// per-wave P, swizzled
    __shared__ int s_merge;

    const int lane = threadIdx.x & 63, wave = threadIdx.x >> 6;
    const int quad = lane >> 4, l15 = lane & 15;
    const int bh = blockIdx.x;
    const int qt   = g_sched[blockIdx.y * 4 + 0];
    const int klo  = g_sched[blockIdx.y * 4 + 1];
    const int khi  = g_sched[blockIdx.y * 4 + 2];
    const int part = g_sched[blockIdx.y * 4 + 3];
    const int q0 = qt * 64;
    const float M0 = 12.0f;                  // fixed max (log2 domain)

    // ---- Q B-frags from Qt [bh][d][s] (pre-scaled): lane = q column ----
    bf16x8 qf0, qf1;
    {
        const unsigned short* qb = Qt + (size_t)bh * HD * S_LEN + q0 + wave * 16 + l15;
        union { bf16x8 v; unsigned short u[8]; } u0, u1;
        #pragma unroll
        for (int j = 0; j < 8; ++j) {
            u0.u[j] = qb[(quad * 8 + j) * S_LEN];
            u1.u[j] = qb[(32 + quad * 8 + j) * S_LEN];
        }
        qf0 = u0.v; qf1 = u1.v;
    }

    f32x4 Z[4];
    #pragma unroll
    for (int i = 0; i < 4; ++i) Z[i] = (f32x4){0.f, 0.f, 0.f, 0.f};
    float rsum = 0.f;

    unsigned short* pw = Pl + wave * 1024;
    const int pwrow = l15 * 64;
    const int qthr  = wave * 16 + l15 - quad * 4;   // mask if n*16+r > qthr

    for (int kt = klo; kt <= khi; ++kt) {
        __syncthreads();
        #pragma unroll
        for (int i = 0; i < 2; ++i) {       // K tile [key][d]
            int c0 = (i * 4 + wave) * 64;
            int c  = c0 + lane;
            int r = c >> 3, pc = c & 7, q = pc ^ (r & 7);
            GLDS16(Kh + ((size_t)bh * S_LEN + kt * 64 + r) * HD + q * 8, Ks + c0 * 8);
        }
        #pragma unroll
        for (int i = 0; i < 2; ++i) {       // V tile [d][key]
            int c0 = (i * 4 + wave) * 64;
            int c  = c0 + lane;
            int d = c >> 3, pc = c & 7, q = pc ^ (d & 7);
            GLDS16(Vt + ((size_t)bh * HD + d) * S_LEN + kt * 64 + q * 8, Vs + c0 * 8);
        }
        __syncthreads();

        const bool diag = (kt == qt);
        const int nmax = diag ? wave : 3;

        // ---- S^T tiles: rows = keys, col = q. p = exp2(s - M0), pack to pw ----
        #pragma unroll
        for (int n = 0; n < 4; ++n) {
            int woff = pwrow + (((2 * n + (quad >> 1)) ^ (l15 & 7)) << 3) + (quad & 1) * 4;
            if (n <= nmax) {
                int rk = n * 16 + l15;       // A-operand: lane = key row
                int x = rk & 7;
                bf16x8 kv0 = *(const bf16x8*)(Ks + rk * 64 + ((quad    ) ^ x) * 8);
                bf16x8 kv1 = *(const bf16x8*)(Ks + rk * 64 + ((4 + quad) ^ x) * 8);
                f32x4 t4 = (f32x4){-M0, -M0, -M0, -M0};
                t4 = __builtin_amdgcn_mfma_f32_16x16x32_bf16(kv0, qf0, t4, 0, 0, 0);
                t4 = __builtin_amdgcn_mfma_f32_16x16x32_bf16(kv1, qf1, t4, 0, 0, 0);
                float p[4];
                #pragma unroll
                for (int r = 0; r < 4; ++r) {
                    p[r] = exp2f(t4[r]);
                    if (diag && (n * 16 + r) > qthr) p[r] = 0.f;
                    rsum += p[r];
                }
                uint2 pk;
                pk.x = pk_trunc(p[0], p[1]);
                pk.y = pk_trunc(p[2], p[3]);
                *(uint2*)(pw + woff) = pk;
            } else {
                *(uint2*)(pw + woff) = (uint2){0u, 0u};
            }
        }

        // ---- Z^T += V^T P ----
        const int khmax = diag ? (wave >> 1) : 1;
        for (int kh = 0; kh <= khmax; ++kh) {
            bf16x8 pa = *(const bf16x8*)(pw + pwrow + ((kh * 4 + quad) ^ (l15 & 7)) * 8);
            #pragma unroll
            for (int ni = 0; ni < 4; ++ni) {
                int rd = ni * 16 + l15;      // A-operand: lane = d row
                bf16x8 vb = *(const bf16x8*)(Vs + rd * 64 + ((kh * 4 + quad) ^ (rd & 7)) * 8);
                Z[ni] = __builtin_amdgcn_mfma_f32_16x16x32_bf16(vb, pa, Z[ni], 0, 0, 0);
            }
        }
    }

    // ---- combine quad partial sums (disjoint key subsets per quad) ----
    rsum += __shfl_xor(rsum, 16);
    rsum += __shfl_xor(rsum, 32);

    const int ql = wave * 16 + l15;          // q within 64-tile (lane = q column)
    const int b = bh >> 4, h = bh & (NH - 1);
    if (part < 0) {
        float inv = 1.f / rsum;
        size_t rowoff = (size_t)(b * S_LEN + q0 + ql) * DMODEL + h * HD;
        #pragma unroll
        for (int ni = 0; ni < 4; ++ni) {
            ushort4 o;
            o.x = f2bf(Z[ni][0] * inv);
            o.y = f2bf(Z[ni][1] * inv);
            o.z = f2bf(Z[ni][2] * inv);
            o.w = f2bf(Z[ni][3] * inv);
            *(ushort4*)(zb + rowoff + ni * 16 + quad * 4) = o;
        }
    } else {
        const int qi = qt - 17;
        const int slot = qi * 2 + part;
        float* zpo = Zp + ((size_t)(slot * 32 + bh) * 64) * 64;
        #pragma unroll
        for (int ni = 0; ni < 4; ++ni) {
            float4 st;
            st.x = Z[ni][0]; st.y = Z[ni][1]; st.z = Z[ni][2]; st.w = Z[ni][3];
            *(float4*)(zpo + (size_t)ql * 64 + ni * 16 + quad * 4) = st;
        }
        if (quad == 0)
            lp[(size_t)(slot * 32 + bh) * 64 + ql] = rsum;

        // ---- threadfence-reduction: second finisher merges the pair ----
        __threadfence();
        __syncthreads();
        if (threadIdx.x == 0)
            s_merge = atomicAdd(&flags[qi * 32 + bh], 1);
        __syncthreads();
        if (s_merge == 1) {
            __threadfence();                 // acquire: partner's Zp/lp visible
            const int t = threadIdx.x;
            const int q = t >> 2;            // 0..63
            const int d0 = (t & 3) << 4;     // 0,16,32,48
            const int s0 = qi * 2, s1 = s0 + 1;
            float l = lp[(size_t)(s0 * 32 + bh) * 64 + q] +
                      lp[(size_t)(s1 * 32 + bh) * 64 + q];
            float inv = 1.f / l;
            const float* z0 = Zp + ((size_t)(s0 * 32 + bh) * 64 + q) * 64 + d0;
            const float* z1 = Zp + ((size_t)(s1 * 32 + bh) * 64 + q) * 64 + d0;
            unsigned short* o =
                zb + (size_t)(b * S_LEN + qt * 64 + q) * DMODEL + h * HD + d0;
            #pragma unroll
            for (int i = 0; i < 16; i += 4) {
                float4 a = *(const float4*)(z0 + i);
                float4 c = *(const float4*)(z1 + i);
                ushort4 ov;
                ov.x = f2bf((a.x + c.x) * inv);
                ov.y = f2bf((a.y + c.y) * inv);
                ov.z = f2bf((a.z + c.z) * inv);
                ov.w = f2bf((a.w + c.w) * inv);
                *(ushort4*)(o + i) = ov;
            }
        }
    }
}

// ---------------------------------------------------------------------------
extern "C" void kernel_launch(void* const* d_in, const int* in_sizes, int n_in,
                              void* d_out, int out_size, void* d_ws, size_t ws_size,
                              hipStream_t stream)
{
    const float* x     = (const float*)d_in[0];
    const float* w_qkv = (const float*)d_in[1];
    const float* b_qkv = (const float*)d_in[2];
    const float* w_out = (const float*)d_in[3];
    const float* b_out = (const float*)d_in[4];
    float* out = (float*)d_out;

    unsigned short* wsu   = (unsigned short*)d_ws;
    unsigned short* xb    = wsu;                       // 4096*1024
    unsigned short* wqkvT = xb    + (size_t)4194304;   // 3072*1024
    unsigned short* woutT = wqkvT + (size_t)3145728;   // 1024*1024
    unsigned short* Qt    = woutT + (size_t)1048576;   // 32*64*2048 (pre-scaled)
    unsigned short* Kh    = Qt    + (size_t)4194304;
    unsigned short* Vt    = Kh    + (size_t)4194304;
    unsigned short* zb    = Vt    + (size_t)4194304;   // 4096*1024
    float* Zp  = (float*)(zb + (size_t)4194304);       // 30*32*64*64 fp32
    float* lp  = Zp + (size_t)30 * 32 * 64 * 64;       // 30*32*64 fp32
    int*   flags = (int*)(lp + (size_t)30 * 32 * 64);  // 15*32 ints

    const int M = 2 * S_LEN;   // 4096

    prep_kernel<<<dim3(8192), 256, 0, stream>>>(x, w_qkv, w_out, xb, wqkvT, woutT, flags);

    gemm_qkv_kernel<<<dim3(3 * DMODEL / 128, M / 128), 256, 0, stream>>>(
        xb, wqkvT, b_qkv, Qt, Kh, Vt);

    attn_mfma_kernel<<<dim3(2 * NH, 47), 256, 0, stream>>>(Qt, Kh, Vt, zb, Zp, lp, flags);

    gemm_out_kernel<<<dim3(DMODEL / 128, M / 128), 256, 0, stream>>>(
        zb, woutT, b_out, out);
}

// Round 6
// 197.122 us; speedup vs baseline: 1.8898x; 1.8898x over previous
//
#include <hip/hip_runtime.h>

#define S_LEN  2048
#define NH     16
#define HD     64
#define DMODEL 1024

using bf16x8 = __attribute__((ext_vector_type(8))) __bf16;
using f32x4  = __attribute__((ext_vector_type(4))) float;

__device__ __forceinline__ unsigned short f2bf(float f) {
    unsigned u = __float_as_uint(f);
    u += 0x7FFFu + ((u >> 16) & 1u);   // RNE
    return (unsigned short)(u >> 16);
}
// pack trunc(a)->lo, trunc(b)->hi in one v_perm
__device__ __forceinline__ unsigned pk_trunc(float lo, float hi) {
    return __builtin_amdgcn_perm(__float_as_uint(hi), __float_as_uint(lo), 0x07060302u);
}

// async global->LDS, 16B per lane; dest = wave-uniform base + lane*16
#define GLDS16(gsrc, ldst) \
    __builtin_amdgcn_global_load_lds((__attribute__((address_space(1))) void*)(gsrc), \
                                     (__attribute__((address_space(3))) void*)(ldst), 16, 0, 0)

#define WAIT_LGKM0() __builtin_amdgcn_s_waitcnt(0xC07F)   // lgkmcnt(0) only

// ---------------------------------------------------------------------------
// Fused prep: x fp32->bf16 (blocks 0..4095), weight transpose+convert
// (blocks 4096..8191). NO fences/atomics anywhere (R5 lesson: agent-scope
// fences invalidate L2 and destroy co-resident kernels' locality).
// ---------------------------------------------------------------------------
__global__ __launch_bounds__(256) void prep_kernel(
    const float* __restrict__ x, const float* __restrict__ w_qkv,
    const float* __restrict__ w_out,
    unsigned short* __restrict__ xb, unsigned short* __restrict__ wqkvT,
    unsigned short* __restrict__ woutT) {
    __shared__ float T[32][33];
    int bx = blockIdx.x;
    if (bx < 4096) {
        int idx = (bx * 256 + threadIdx.x) * 4;
        float4 v = *(const float4*)(x + idx);
        ushort4 o;
        o.x = f2bf(v.x); o.y = f2bf(v.y); o.z = f2bf(v.z); o.w = f2bf(v.w);
        *(ushort4*)(xb + idx) = o;
        return;
    }
    int tb = bx - 4096;
    int tcol = tb & 127, krow = tb >> 7;
    const float* in;
    unsigned short* out;
    int N, nbx;
    if (tcol < 96) { in = w_qkv; out = wqkvT; N = 3072; nbx = tcol; }
    else           { in = w_out; out = woutT; N = 1024; nbx = tcol - 96; }
    int r  = threadIdx.x >> 3;
    int c4 = (threadIdx.x & 7) * 4;
    int kbase = krow * 32, nbase = nbx * 32;
    float4 v = *(const float4*)(in + (size_t)(kbase + r) * N + nbase + c4);
    T[r][c4 + 0] = v.x; T[r][c4 + 1] = v.y; T[r][c4 + 2] = v.z; T[r][c4 + 3] = v.w;
    __syncthreads();
    ushort4 o;
    o.x = f2bf(T[c4 + 0][r]); o.y = f2bf(T[c4 + 1][r]);
    o.z = f2bf(T[c4 + 2][r]); o.w = f2bf(T[c4 + 3][r]);
    *(ushort4*)(out + (size_t)(nbase + r) * 1024 + kbase + c4) = o;
}

// ---------------------------------------------------------------------------
// MFMA NT GEMM mainloop, BK=64: halves barrier pairs vs BK=32.
// A[M,K], B[N,K] bf16 k-contiguous. LDS 2x16KB, 8-chunk/row XOR swizzle.
// 4 waves, each a 64x64 sub-tile: 4x4x(2 k-halves) = 32 MFMA per stage.
// ---------------------------------------------------------------------------
__device__ __forceinline__ void mfma_mainloop64(const unsigned short* __restrict__ A,
                                                const unsigned short* __restrict__ B,
                                                int K, int m0, int n0,
                                                unsigned short* As, unsigned short* Bs,
                                                f32x4 acc[4][4]) {
    const int lane = threadIdx.x & 63, wave = threadIdx.x >> 6;
    const int quad = lane >> 4, l15 = lane & 15;
    const int wm0 = (wave >> 1) * 64, wn0 = (wave & 1) * 64;

    for (int k0 = 0; k0 < K; k0 += 64) {
        __syncthreads();
        #pragma unroll
        for (int j = 0; j < 8; ++j) {
            int c0 = (j & 3) * 256 + wave * 64;   // chunk base, wave-uniform
            int c  = c0 + lane;
            int r = c >> 3, pc = c & 7, q = pc ^ (r & 7);
            if (j < 4)
                GLDS16(A + (size_t)(m0 + r) * K + k0 + q * 8, As + c0 * 8);
            else
                GLDS16(B + (size_t)(n0 + r) * K + k0 + q * 8, Bs + c0 * 8);
        }
        __syncthreads();

        bf16x8 af[2][4], bfr[2][4];
        #pragma unroll
        for (int mi = 0; mi < 4; ++mi) {
            int r = wm0 + mi * 16 + l15, x = r & 7;
            af[0][mi] = *(const bf16x8*)(As + r * 64 + ((quad    ) ^ x) * 8);
            af[1][mi] = *(const bf16x8*)(As + r * 64 + ((4 + quad) ^ x) * 8);
        }
        #pragma unroll
        for (int ni = 0; ni < 4; ++ni) {
            int r = wn0 + ni * 16 + l15, x = r & 7;
            bfr[0][ni] = *(const bf16x8*)(Bs + r * 64 + ((quad    ) ^ x) * 8);
            bfr[1][ni] = *(const bf16x8*)(Bs + r * 64 + ((4 + quad) ^ x) * 8);
        }
        #pragma unroll
        for (int h = 0; h < 2; ++h)
            #pragma unroll
            for (int mi = 0; mi < 4; ++mi)
                #pragma unroll
                for (int ni = 0; ni < 4; ++ni)
                    acc[mi][ni] = __builtin_amdgcn_mfma_f32_16x16x32_bf16(
                        af[h][mi], bfr[h][ni], acc[mi][ni], 0, 0, 0);
    }
}

// ---------------------------------------------------------------------------
// GEMM1: qkv projection. LDS-transpose epilogue -> dwordx4 stores.
// Q -> Qt [bh][d][s] PRE-SCALED by 1/sqrt(64)*log2e, K -> Kh [bh][s][d],
// V -> Vt [bh][d][s].
// ---------------------------------------------------------------------------
__global__ __launch_bounds__(256) void gemm_qkv_kernel(
    const unsigned short* __restrict__ xb, const unsigned short* __restrict__ wT,
    const float* __restrict__ bias,
    unsigned short* __restrict__ Qt, unsigned short* __restrict__ Kh,
    unsigned short* __restrict__ Vt) {
    __shared__ __align__(16) unsigned short Sh[16384];  // As | Bs, reused by epilogue
    unsigned short* As = Sh;
    unsigned short* Bs = Sh + 8192;

    f32x4 acc[4][4];
    #pragma unroll
    for (int i = 0; i < 4; ++i)
        #pragma unroll
        for (int j = 0; j < 4; ++j) acc[i][j] = (f32x4){0.f, 0.f, 0.f, 0.f};

    int m0 = blockIdx.y * 128, n0 = blockIdx.x * 128;
    mfma_mainloop64(xb, wT, DMODEL, m0, n0, As, Bs, acc);

    const int lane = threadIdx.x & 63, wave = threadIdx.x >> 6;
    const int quad = lane >> 4, l15 = lane & 15;
    const int wm0 = (wave >> 1) * 64, wn0 = (wave & 1) * 64;

    const int colbase = n0 + wn0;            // 64-aligned -> uniform t,h per wave
    const int t = colbase >> 10;
    const int h = (colbase >> 6) & (NH - 1);
    const float qscale = (t == 0) ? 0.125f * 1.44269504088896f : 1.0f;
    float bv[4];
    #pragma unroll
    for (int ni = 0; ni < 4; ++ni) bv[ni] = bias[colbase + ni * 16 + l15];

    __syncthreads();                         // everyone done reading As/Bs
    unsigned short* Lw = Sh + wave * 1536;   // per-wave scratch (3 KB)

    #pragma unroll
    for (int mi = 0; mi < 4; ++mi) {
        int mbase = m0 + wm0 + mi * 16;
        int b = mbase >> 11, sbase = mbase & (S_LEN - 1);
        if (t == 1) {
            // K: want [s][d] rows; Lw[r*72 + c]
            #pragma unroll
            for (int ni = 0; ni < 4; ++ni)
                #pragma unroll
                for (int r = 0; r < 4; ++r)
                    Lw[(quad * 4 + r) * 72 + ni * 16 + l15] =
                        f2bf(acc[mi][ni][r] + bv[ni]);
            WAIT_LGKM0();
            int rr = lane & 15, dc = (lane >> 4) * 16;
            uint4 v0 = *(const uint4*)(Lw + rr * 72 + dc);
            uint4 v1 = *(const uint4*)(Lw + rr * 72 + dc + 8);
            unsigned short* dst =
                Kh + ((size_t)(b * NH + h) * S_LEN + sbase + rr) * HD + dc;
            *(uint4*)dst = v0;
            *(uint4*)(dst + 8) = v1;
        } else {
            // Q/V: want [d][s] rows; Lw[c*24 + r]
            #pragma unroll
            for (int ni = 0; ni < 4; ++ni)
                #pragma unroll
                for (int r = 0; r < 4; ++r)
                    Lw[(ni * 16 + l15) * 24 + quad * 4 + r] =
                        f2bf((acc[mi][ni][r] + bv[ni]) * qscale);
            WAIT_LGKM0();
            int c = lane;                    // d within head
            uint4 v0 = *(const uint4*)(Lw + c * 24);
            uint4 v1 = *(const uint4*)(Lw + c * 24 + 8);
            unsigned short* base = (t == 0) ? Qt : Vt;
            unsigned short* dst =
                base + ((size_t)(b * NH + h) * HD + c) * S_LEN + sbase;
            *(uint4*)dst = v0;
            *(uint4*)(dst + 8) = v1;
        }
        WAIT_LGKM0();                        // stores consumed Lw before next mi
    }
}

// ---------------------------------------------------------------------------
// GEMM3: out = zb @ w_outT + b_out, fp32 output
// ---------------------------------------------------------------------------
__global__ __launch_bounds__(256) void gemm_out_kernel(
    const unsigned short* __restrict__ zb, const unsigned short* __restrict__ wT,
    const float* __restrict__ bias, float* __restrict__ out) {
    __shared__ __align__(16) unsigned short As[8192], Bs[8192];
    f32x4 acc[4][4];
    #pragma unroll
    for (int i = 0; i < 4; ++i)
        #pragma unroll
        for (int j = 0; j < 4; ++j) acc[i][j] = (f32x4){0.f, 0.f, 0.f, 0.f};

    int m0 = blockIdx.y * 128, n0 = blockIdx.x * 128;
    mfma_mainloop64(zb, wT, DMODEL, m0, n0, As, Bs, acc);

    const int lane = threadIdx.x & 63, wave = threadIdx.x >> 6;
    const int quad = lane >> 4, l15 = lane & 15;
    const int wm0 = (wave >> 1) * 64, wn0 = (wave & 1) * 64;
    #pragma unroll
    for (int mi = 0; mi < 4; ++mi) {
        #pragma unroll
        for (int ni = 0; ni < 4; ++ni) {
            int col = n0 + wn0 + ni * 16 + l15;
            float bvv = bias[col];
            #pragma unroll
            for (int r = 0; r < 4; ++r)
                out[(size_t)(m0 + wm0 + mi * 16 + quad * 4 + r) * DMODEL + col] =
                    acc[mi][ni][r] + bvv;
        }
    }
}

// ---------------------------------------------------------------------------
// Balanced causal schedule: 47 entries {qt, kt_lo, kt_hi, part}, size-descending.
// ---------------------------------------------------------------------------
__device__ const int g_sched[47 * 4] = {
    16,0,16,-1,
    31,0,15,0,  31,16,31,1,  30,0,15,0,  15,0,15,-1,
    30,16,30,1, 29,0,14,0,   29,15,29,1, 28,0,14,0,  14,0,14,-1,
    28,15,28,1, 27,0,13,0,   27,14,27,1, 26,0,13,0,  13,0,13,-1,
    26,14,26,1, 25,0,12,0,   25,13,25,1, 24,0,12,0,  12,0,12,-1,
    24,13,24,1, 23,0,11,0,   23,12,23,1, 22,0,11,0,  11,0,11,-1,
    22,12,22,1, 21,0,10,0,   21,11,21,1, 20,0,10,0,  10,0,10,-1,
    20,11,20,1, 19,0,9,0,    19,10,19,1, 18,0,9,0,   9,0,9,-1,
    18,10,18,1, 17,0,8,0,    17,9,17,1,  8,0,8,-1,
    7,0,7,-1, 6,0,6,-1, 5,0,5,-1, 4,0,4,-1, 3,0,3,-1, 2,0,2,-1, 1,0,1,-1, 0,0,0,-1
};

// ---------------------------------------------------------------------------
// Flash attention, S^T orientation: S^T = K Q^T (C/D col=q!), Z^T = V^T P.
// Per lane: 4 consecutive keys x 1 q-column -> P staged as packed ds_write_b64,
// row-sums in-lane. Fixed-max softmax (Q pre-scaled, acc init -M0).
// R6: identical to round-4 version (no fences/atomics — R5 regression).
// ---------------------------------------------------------------------------
__global__ __launch_bounds__(256) void attn_mfma_kernel(
    const unsigned short* __restrict__ Qt, const unsigned short* __restrict__ Kh,
    const unsigned short* __restrict__ Vt, unsigned short* __restrict__ zb,
    float* __restrict__ Zp, float* __restrict__ lp) {
    __shared__ __align__(16) unsigned short Ks[64 * 64];    // [key][d], swizzled
    __shared__ __align__(16) unsigned short Vs[64 * 64];    // [d][key], swizzled
    __shared__ __align__(16) unsigned short Pl[4 * 16 * 64];// per-wave P, swizzled

    const int lane = threadIdx.x & 63, wave = threadIdx.x >> 6;
    const int quad = lane >> 4, l15 = lane & 15;
    const int bh = blockIdx.x;
    const int qt   = g_sched[blockIdx.y * 4 + 0];
    const int klo  = g_sched[blockIdx.y * 4 + 1];
    const int khi  = g_sched[blockIdx.y * 4 + 2];
    const int part = g_sched[blockIdx.y * 4 + 3];
    const int q0 = qt * 64;
    const float M0 = 12.0f;                  // fixed max (log2 domain)

    // ---- Q B-frags from Qt [bh][d][s] (pre-scaled): lane = q column ----
    bf16x8 qf0, qf1;
    {
        const unsigned short* qb = Qt + (size_t)bh * HD * S_LEN + q0 + wave * 16 + l15;
        union { bf16x8 v; unsigned short u[8]; } u0, u1;
        #pragma unroll
        for (int j = 0; j < 8; ++j) {
            u0.u[j] = qb[(quad * 8 + j) * S_LEN];
            u1.u[j] = qb[(32 + quad * 8 + j) * S_LEN];
        }
        qf0 = u0.v; qf1 = u1.v;
    }

    f32x4 Z[4];
    #pragma unroll
    for (int i = 0; i < 4; ++i) Z[i] = (f32x4){0.f, 0.f, 0.f, 0.f};
    float rsum = 0.f;

    unsigned short* pw = Pl + wave * 1024;
    const int pwrow = l15 * 64;
    const int qthr  = wave * 16 + l15 - quad * 4;   // mask if n*16+r > qthr

    for (int kt = klo; kt <= khi; ++kt) {
        __syncthreads();
        #pragma unroll
        for (int i = 0; i < 2; ++i) {       // K tile [key][d]
            int c0 = (i * 4 + wave) * 64;
            int c  = c0 + lane;
            int r = c >> 3, pc = c & 7, q = pc ^ (r & 7);
            GLDS16(Kh + ((size_t)bh * S_LEN + kt * 64 + r) * HD + q * 8, Ks + c0 * 8);
        }
        #pragma unroll
        for (int i = 0; i < 2; ++i) {       // V tile [d][key]
            int c0 = (i * 4 + wave) * 64;
            int c  = c0 + lane;
            int d = c >> 3, pc = c & 7, q = pc ^ (d & 7);
            GLDS16(Vt + ((size_t)bh * HD + d) * S_LEN + kt * 64 + q * 8, Vs + c0 * 8);
        }
        __syncthreads();

        const bool diag = (kt == qt);
        const int nmax = diag ? wave : 3;

        // ---- S^T tiles: rows = keys, col = q. p = exp2(s - M0), pack to pw ----
        #pragma unroll
        for (int n = 0; n < 4; ++n) {
            int woff = pwrow + (((2 * n + (quad >> 1)) ^ (l15 & 7)) << 3) + (quad & 1) * 4;
            if (n <= nmax) {
                int rk = n * 16 + l15;       // A-operand: lane = key row
                int x = rk & 7;
                bf16x8 kv0 = *(const bf16x8*)(Ks + rk * 64 + ((quad    ) ^ x) * 8);
                bf16x8 kv1 = *(const bf16x8*)(Ks + rk * 64 + ((4 + quad) ^ x) * 8);
                f32x4 t4 = (f32x4){-M0, -M0, -M0, -M0};
                t4 = __builtin_amdgcn_mfma_f32_16x16x32_bf16(kv0, qf0, t4, 0, 0, 0);
                t4 = __builtin_amdgcn_mfma_f32_16x16x32_bf16(kv1, qf1, t4, 0, 0, 0);
                float p[4];
                #pragma unroll
                for (int r = 0; r < 4; ++r) {
                    p[r] = exp2f(t4[r]);
                    if (diag && (n * 16 + r) > qthr) p[r] = 0.f;
                    rsum += p[r];
                }
                uint2 pk;
                pk.x = pk_trunc(p[0], p[1]);
                pk.y = pk_trunc(p[2], p[3]);
                *(uint2*)(pw + woff) = pk;
            } else {
                *(uint2*)(pw + woff) = (uint2){0u, 0u};
            }
        }

        // ---- Z^T += V^T P ----
        const int khmax = diag ? (wave >> 1) : 1;
        for (int kh = 0; kh <= khmax; ++kh) {
            bf16x8 pa = *(const bf16x8*)(pw + pwrow + ((kh * 4 + quad) ^ (l15 & 7)) * 8);
            #pragma unroll
            for (int ni = 0; ni < 4; ++ni) {
                int rd = ni * 16 + l15;      // A-operand: lane = d row
                bf16x8 vb = *(const bf16x8*)(Vs + rd * 64 + ((kh * 4 + quad) ^ (rd & 7)) * 8);
                Z[ni] = __builtin_amdgcn_mfma_f32_16x16x32_bf16(vb, pa, Z[ni], 0, 0, 0);
            }
        }
    }

    // ---- combine quad partial sums (disjoint key subsets per quad) ----
    rsum += __shfl_xor(rsum, 16);
    rsum += __shfl_xor(rsum, 32);

    const int ql = wave * 16 + l15;          // q within 64-tile (lane = q column)
    if (part < 0) {
        const int b = bh >> 4, h = bh & (NH - 1);
        float inv = 1.f / rsum;
        size_t rowoff = (size_t)(b * S_LEN + q0 + ql) * DMODEL + h * HD;
        #pragma unroll
        for (int ni = 0; ni < 4; ++ni) {
            ushort4 o;
            o.x = f2bf(Z[ni][0] * inv);
            o.y = f2bf(Z[ni][1] * inv);
            o.z = f2bf(Z[ni][2] * inv);
            o.w = f2bf(Z[ni][3] * inv);
            *(ushort4*)(zb + rowoff + ni * 16 + quad * 4) = o;
        }
    } else {
        const int slot = (qt - 17) * 2 + part;
        float* zpo = Zp + ((size_t)(slot * 32 + bh) * 64) * 64;
        #pragma unroll
        for (int ni = 0; ni < 4; ++ni) {
            float4 st;
            st.x = Z[ni][0]; st.y = Z[ni][1]; st.z = Z[ni][2]; st.w = Z[ni][3];
            *(float4*)(zpo + (size_t)ql * 64 + ni * 16 + quad * 4) = st;
        }
        if (quad == 0)
            lp[(size_t)(slot * 32 + bh) * 64 + ql] = rsum;
    }
}

// ---------------------------------------------------------------------------
// Merge additive partials: zb = (Z0+Z1)/(l0+l1), grid (32 bh, 15 split qt)
// ---------------------------------------------------------------------------
__global__ __launch_bounds__(256) void attn_merge_kernel(
    const float* __restrict__ Zp, const float* __restrict__ lp,
    unsigned short* __restrict__ zb) {
    const int bh = blockIdx.x, qi = blockIdx.y, qt = 17 + qi;
    const int t = threadIdx.x;
    const int q = t >> 2;             // 0..63
    const int d0 = (t & 3) << 4;      // 0,16,32,48
    const int s0 = qi * 2, s1 = s0 + 1;
    float l = lp[(size_t)(s0 * 32 + bh) * 64 + q] +
              lp[(size_t)(s1 * 32 + bh) * 64 + q];
    float inv = 1.f / l;
    const float* z0 = Zp + ((size_t)(s0 * 32 + bh) * 64 + q) * 64 + d0;
    const float* z1 = Zp + ((size_t)(s1 * 32 + bh) * 64 + q) * 64 + d0;
    const int b = bh >> 4, h = bh & (NH - 1);
    unsigned short* o =
        zb + (size_t)(b * S_LEN + qt * 64 + q) * DMODEL + h * HD + d0;
    #pragma unroll
    for (int i = 0; i < 16; i += 4) {
        float4 a = *(const float4*)(z0 + i);
        float4 c = *(const float4*)(z1 + i);
        ushort4 ov;
        ov.x = f2bf((a.x + c.x) * inv);
        ov.y = f2bf((a.y + c.y) * inv);
        ov.z = f2bf((a.z + c.z) * inv);
        ov.w = f2bf((a.w + c.w) * inv);
        *(ushort4*)(o + i) = ov;
    }
}

// ---------------------------------------------------------------------------
extern "C" void kernel_launch(void* const* d_in, const int* in_sizes, int n_in,
                              void* d_out, int out_size, void* d_ws, size_t ws_size,
                              hipStream_t stream)
{
    const float* x     = (const float*)d_in[0];
    const float* w_qkv = (const float*)d_in[1];
    const float* b_qkv = (const float*)d_in[2];
    const float* w_out = (const float*)d_in[3];
    const float* b_out = (const float*)d_in[4];
    float* out = (float*)d_out;

    unsigned short* wsu   = (unsigned short*)d_ws;
    unsigned short* xb    = wsu;                       // 4096*1024
    unsigned short* wqkvT = xb    + (size_t)4194304;   // 3072*1024
    unsigned short* woutT = wqkvT + (size_t)3145728;   // 1024*1024
    unsigned short* Qt    = woutT + (size_t)1048576;   // 32*64*2048 (pre-scaled)
    unsigned short* Kh    = Qt    + (size_t)4194304;
    unsigned short* Vt    = Kh    + (size_t)4194304;
    unsigned short* zb    = Vt    + (size_t)4194304;   // 4096*1024
    float* Zp = (float*)(zb + (size_t)4194304);        // 30*32*64*64 fp32
    float* lp = Zp + (size_t)30 * 32 * 64 * 64;        // 30*32*64 fp32

    const int M = 2 * S_LEN;   // 4096

    prep_kernel<<<dim3(8192), 256, 0, stream>>>(x, w_qkv, w_out, xb, wqkvT, woutT);

    gemm_qkv_kernel<<<dim3(3 * DMODEL / 128, M / 128), 256, 0, stream>>>(
        xb, wqkvT, b_qkv, Qt, Kh, Vt);

    attn_mfma_kernel<<<dim3(2 * NH, 47), 256, 0, stream>>>(Qt, Kh, Vt, zb, Zp, lp);
    attn_merge_kernel<<<dim3(2 * NH, 15), 256, 0, stream>>>(Zp, lp, zb);

    gemm_out_kernel<<<dim3(DMODEL / 128, M / 128), 256, 0, stream>>>(
        zb, woutT, b_out, out);
}

// Round 7
// 191.034 us; speedup vs baseline: 1.9500x; 1.0319x over previous
//
#include <hip/hip_runtime.h>

#define S_LEN  2048
#define NH     16
#define HD     64
#define DMODEL 1024

using bf16x8 = __attribute__((ext_vector_type(8))) __bf16;
using f32x4  = __attribute__((ext_vector_type(4))) float;

__device__ __forceinline__ unsigned short f2bf(float f) {
    unsigned u = __float_as_uint(f);
    u += 0x7FFFu + ((u >> 16) & 1u);   // RNE
    return (unsigned short)(u >> 16);
}
// pack trunc(a)->lo, trunc(b)->hi in one v_perm
__device__ __forceinline__ unsigned pk_trunc(float lo, float hi) {
    return __builtin_amdgcn_perm(__float_as_uint(hi), __float_as_uint(lo), 0x07060302u);
}

// async global->LDS, 16B per lane; dest = wave-uniform base + lane*16
#define GLDS16(gsrc, ldst) \
    __builtin_amdgcn_global_load_lds((__attribute__((address_space(1))) void*)(gsrc), \
                                     (__attribute__((address_space(3))) void*)(ldst), 16, 0, 0)

#define WAIT_LGKM0() __builtin_amdgcn_s_waitcnt(0xC07F)   // lgkmcnt(0) only

// ---------------------------------------------------------------------------
// Fused prep: x fp32->bf16 (blocks 0..4095), weight transpose+convert
// (blocks 4096..8191). No fences/atomics (R5 lesson).
// ---------------------------------------------------------------------------
__global__ __launch_bounds__(256) void prep_kernel(
    const float* __restrict__ x, const float* __restrict__ w_qkv,
    const float* __restrict__ w_out,
    unsigned short* __restrict__ xb, unsigned short* __restrict__ wqkvT,
    unsigned short* __restrict__ woutT) {
    __shared__ float T[32][33];
    int bx = blockIdx.x;
    if (bx < 4096) {
        int idx = (bx * 256 + threadIdx.x) * 4;
        float4 v = *(const float4*)(x + idx);
        ushort4 o;
        o.x = f2bf(v.x); o.y = f2bf(v.y); o.z = f2bf(v.z); o.w = f2bf(v.w);
        *(ushort4*)(xb + idx) = o;
        return;
    }
    int tb = bx - 4096;
    int tcol = tb & 127, krow = tb >> 7;
    const float* in;
    unsigned short* out;
    int N, nbx;
    if (tcol < 96) { in = w_qkv; out = wqkvT; N = 3072; nbx = tcol; }
    else           { in = w_out; out = woutT; N = 1024; nbx = tcol - 96; }
    int r  = threadIdx.x >> 3;
    int c4 = (threadIdx.x & 7) * 4;
    int kbase = krow * 32, nbase = nbx * 32;
    float4 v = *(const float4*)(in + (size_t)(kbase + r) * N + nbase + c4);
    T[r][c4 + 0] = v.x; T[r][c4 + 1] = v.y; T[r][c4 + 2] = v.z; T[r][c4 + 3] = v.w;
    __syncthreads();
    ushort4 o;
    o.x = f2bf(T[c4 + 0][r]); o.y = f2bf(T[c4 + 1][r]);
    o.z = f2bf(T[c4 + 2][r]); o.w = f2bf(T[c4 + 3][r]);
    *(ushort4*)(out + (size_t)(nbase + r) * 1024 + kbase + c4) = o;
}

// ---------------------------------------------------------------------------
// MFMA NT GEMM mainloop, BK=64, tile 128 x (NI*32). NI=4 -> 128x128 (Bs 16KB),
// NI=2 -> 128x64 (Bs 8KB). 4 waves in 2x2; wave subtile 64 x (NI*16).
// LDS 8-chunk/row XOR swizzle.
// ---------------------------------------------------------------------------
template <int NI>
__device__ __forceinline__ void mfma_mainloop64(const unsigned short* __restrict__ A,
                                                const unsigned short* __restrict__ B,
                                                int K, int m0, int n0,
                                                unsigned short* As, unsigned short* Bs,
                                                f32x4 acc[4][NI]) {
    const int lane = threadIdx.x & 63, wave = threadIdx.x >> 6;
    const int quad = lane >> 4, l15 = lane & 15;
    const int wm0 = (wave >> 1) * 64, wn0 = (wave & 1) * (NI * 16);

    for (int k0 = 0; k0 < K; k0 += 64) {
        __syncthreads();
        #pragma unroll
        for (int j = 0; j < 4 + NI; ++j) {
            if (j < 4) {
                int c0 = j * 256 + wave * 64;
                int c  = c0 + lane;
                int r = c >> 3, pc = c & 7, q = pc ^ (r & 7);
                GLDS16(A + (size_t)(m0 + r) * K + k0 + q * 8, As + c0 * 8);
            } else {
                int c0 = (j - 4) * 256 + wave * 64;
                int c  = c0 + lane;
                int r = c >> 3, pc = c & 7, q = pc ^ (r & 7);
                GLDS16(B + (size_t)(n0 + r) * K + k0 + q * 8, Bs + c0 * 8);
            }
        }
        __syncthreads();

        bf16x8 af[2][4], bfr[2][NI];
        #pragma unroll
        for (int mi = 0; mi < 4; ++mi) {
            int r = wm0 + mi * 16 + l15, x = r & 7;
            af[0][mi] = *(const bf16x8*)(As + r * 64 + ((quad    ) ^ x) * 8);
            af[1][mi] = *(const bf16x8*)(As + r * 64 + ((4 + quad) ^ x) * 8);
        }
        #pragma unroll
        for (int ni = 0; ni < NI; ++ni) {
            int r = wn0 + ni * 16 + l15, x = r & 7;
            bfr[0][ni] = *(const bf16x8*)(Bs + r * 64 + ((quad    ) ^ x) * 8);
            bfr[1][ni] = *(const bf16x8*)(Bs + r * 64 + ((4 + quad) ^ x) * 8);
        }
        #pragma unroll
        for (int h = 0; h < 2; ++h)
            #pragma unroll
            for (int mi = 0; mi < 4; ++mi)
                #pragma unroll
                for (int ni = 0; ni < NI; ++ni)
                    acc[mi][ni] = __builtin_amdgcn_mfma_f32_16x16x32_bf16(
                        af[h][mi], bfr[h][ni], acc[mi][ni], 0, 0, 0);
    }
}

// ---------------------------------------------------------------------------
// GEMM1: qkv projection, 768 blocks, XCD-swizzled tiles: xcd = bid&7 owns
// n-strip [xcd*3, xcd*3+3) (B working set 768KB -> one L2); all XCDs walk m
// together (A shared via L3). Epilogue: LDS transpose -> dwordx4 stores.
// Q -> Qt [bh][d][s] PRE-SCALED by 1/sqrt(64)*log2e, K -> Kh [bh][s][d],
// V -> Vt [bh][d][s].
// ---------------------------------------------------------------------------
__global__ __launch_bounds__(256) void gemm_qkv_kernel(
    const unsigned short* __restrict__ xb, const unsigned short* __restrict__ wT,
    const float* __restrict__ bias,
    unsigned short* __restrict__ Qt, unsigned short* __restrict__ Kh,
    unsigned short* __restrict__ Vt) {
    __shared__ __align__(16) unsigned short Sh[16384];  // As | Bs, reused by epilogue
    unsigned short* As = Sh;
    unsigned short* Bs = Sh + 8192;

    f32x4 acc[4][4];
    #pragma unroll
    for (int i = 0; i < 4; ++i)
        #pragma unroll
        for (int j = 0; j < 4; ++j) acc[i][j] = (f32x4){0.f, 0.f, 0.f, 0.f};

    const int bid = blockIdx.x;
    const int xcd = bid & 7, slot = bid >> 3;          // slot 0..95
    const int nt = xcd * 3 + (slot % 3);               // 0..23
    const int mt = slot / 3;                           // 0..31
    const int m0 = mt * 128, n0 = nt * 128;
    mfma_mainloop64<4>(xb, wT, DMODEL, m0, n0, As, Bs, acc);

    const int lane = threadIdx.x & 63, wave = threadIdx.x >> 6;
    const int quad = lane >> 4, l15 = lane & 15;
    const int wm0 = (wave >> 1) * 64, wn0 = (wave & 1) * 64;

    const int colbase = n0 + wn0;            // 64-aligned -> uniform t,h per wave
    const int t = colbase >> 10;
    const int h = (colbase >> 6) & (NH - 1);
    const float qscale = (t == 0) ? 0.125f * 1.44269504088896f : 1.0f;
    float bv[4];
    #pragma unroll
    for (int ni = 0; ni < 4; ++ni) bv[ni] = bias[colbase + ni * 16 + l15];

    __syncthreads();                         // everyone done reading As/Bs
    unsigned short* Lw = Sh + wave * 1536;   // per-wave scratch (3 KB)

    #pragma unroll
    for (int mi = 0; mi < 4; ++mi) {
        int mbase = m0 + wm0 + mi * 16;
        int b = mbase >> 11, sbase = mbase & (S_LEN - 1);
        if (t == 1) {
            // K: want [s][d] rows; Lw[r*72 + c]
            #pragma unroll
            for (int ni = 0; ni < 4; ++ni)
                #pragma unroll
                for (int r = 0; r < 4; ++r)
                    Lw[(quad * 4 + r) * 72 + ni * 16 + l15] =
                        f2bf(acc[mi][ni][r] + bv[ni]);
            WAIT_LGKM0();
            int rr = lane & 15, dc = (lane >> 4) * 16;
            uint4 v0 = *(const uint4*)(Lw + rr * 72 + dc);
            uint4 v1 = *(const uint4*)(Lw + rr * 72 + dc + 8);
            unsigned short* dst =
                Kh + ((size_t)(b * NH + h) * S_LEN + sbase + rr) * HD + dc;
            *(uint4*)dst = v0;
            *(uint4*)(dst + 8) = v1;
        } else {
            // Q/V: want [d][s] rows; Lw[c*24 + r]
            #pragma unroll
            for (int ni = 0; ni < 4; ++ni)
                #pragma unroll
                for (int r = 0; r < 4; ++r)
                    Lw[(ni * 16 + l15) * 24 + quad * 4 + r] =
                        f2bf((acc[mi][ni][r] + bv[ni]) * qscale);
            WAIT_LGKM0();
            int c = lane;                    // d within head
            uint4 v0 = *(const uint4*)(Lw + c * 24);
            uint4 v1 = *(const uint4*)(Lw + c * 24 + 8);
            unsigned short* base = (t == 0) ? Qt : Vt;
            unsigned short* dst =
                base + ((size_t)(b * NH + h) * HD + c) * S_LEN + sbase;
            *(uint4*)dst = v0;
            *(uint4*)(dst + 8) = v1;
        }
        WAIT_LGKM0();                        // stores consumed Lw before next mi
    }
}

// ---------------------------------------------------------------------------
// GEMM3: out = zb @ w_outT + b_out, fp32. 128x64 tiles -> 512 blocks (2/CU),
// XCD-swizzled: xcd owns n-tiles [2*xcd, 2*xcd+2) (B strip 256KB in L2).
// ---------------------------------------------------------------------------
__global__ __launch_bounds__(256) void gemm_out_kernel(
    const unsigned short* __restrict__ zb, const unsigned short* __restrict__ wT,
    const float* __restrict__ bias, float* __restrict__ out) {
    __shared__ __align__(16) unsigned short As[8192], Bs[4096];
    f32x4 acc[4][2];
    #pragma unroll
    for (int i = 0; i < 4; ++i)
        #pragma unroll
        for (int j = 0; j < 2; ++j) acc[i][j] = (f32x4){0.f, 0.f, 0.f, 0.f};

    const int bid = blockIdx.x;
    const int xcd = bid & 7, slot = bid >> 3;          // slot 0..63
    const int nt = xcd * 2 + (slot & 1);               // 0..15 (64-wide)
    const int mt = slot >> 1;                          // 0..31
    const int m0 = mt * 128, n0 = nt * 64;
    mfma_mainloop64<2>(zb, wT, DMODEL, m0, n0, As, Bs, acc);

    const int lane = threadIdx.x & 63, wave = threadIdx.x >> 6;
    const int quad = lane >> 4, l15 = lane & 15;
    const int wm0 = (wave >> 1) * 64, wn0 = (wave & 1) * 32;
    #pragma unroll
    for (int mi = 0; mi < 4; ++mi) {
        #pragma unroll
        for (int ni = 0; ni < 2; ++ni) {
            int col = n0 + wn0 + ni * 16 + l15;
            float bvv = bias[col];
            #pragma unroll
            for (int r = 0; r < 4; ++r)
                out[(size_t)(m0 + wm0 + mi * 16 + quad * 4 + r) * DMODEL + col] =
                    acc[mi][ni][r] + bvv;
        }
    }
}

// ---------------------------------------------------------------------------
// Balanced causal schedule: 47 entries {qt, kt_lo, kt_hi, part}, size-descending.
// ---------------------------------------------------------------------------
__device__ const int g_sched[47 * 4] = {
    16,0,16,-1,
    31,0,15,0,  31,16,31,1,  30,0,15,0,  15,0,15,-1,
    30,16,30,1, 29,0,14,0,   29,15,29,1, 28,0,14,0,  14,0,14,-1,
    28,15,28,1, 27,0,13,0,   27,14,27,1, 26,0,13,0,  13,0,13,-1,
    26,14,26,1, 25,0,12,0,   25,13,25,1, 24,0,12,0,  12,0,12,-1,
    24,13,24,1, 23,0,11,0,   23,12,23,1, 22,0,11,0,  11,0,11,-1,
    22,12,22,1, 21,0,10,0,   21,11,21,1, 20,0,10,0,  10,0,10,-1,
    20,11,20,1, 19,0,9,0,    19,10,19,1, 18,0,9,0,   9,0,9,-1,
    18,10,18,1, 17,0,8,0,    17,9,17,1,  8,0,8,-1,
    7,0,7,-1, 6,0,6,-1, 5,0,5,-1, 4,0,4,-1, 3,0,3,-1, 2,0,2,-1, 1,0,1,-1, 0,0,0,-1
};

// ---------------------------------------------------------------------------
// Flash attention, S^T orientation: S^T = K Q^T, Z^T = V^T P. Fixed-max
// softmax (Q pre-scaled, acc init -M0). Identical to round-4/6 version.
// ---------------------------------------------------------------------------
__global__ __launch_bounds__(256) void attn_mfma_kernel(
    const unsigned short* __restrict__ Qt, const unsigned short* __restrict__ Kh,
    const unsigned short* __restrict__ Vt, unsigned short* __restrict__ zb,
    float* __restrict__ Zp, float* __restrict__ lp) {
    __shared__ __align__(16) unsigned short Ks[64 * 64];    // [key][d], swizzled
    __shared__ __align__(16) unsigned short Vs[64 * 64];    // [d][key], swizzled
    __shared__ __align__(16) unsigned short Pl[4 * 16 * 64];// per-wave P, swizzled

    const int lane = threadIdx.x & 63, wave = threadIdx.x >> 6;
    const int quad = lane >> 4, l15 = lane & 15;
    const int bh = blockIdx.x;
    const int qt   = g_sched[blockIdx.y * 4 + 0];
    const int klo  = g_sched[blockIdx.y * 4 + 1];
    const int khi  = g_sched[blockIdx.y * 4 + 2];
    const int part = g_sched[blockIdx.y * 4 + 3];
    const int q0 = qt * 64;
    const float M0 = 12.0f;                  // fixed max (log2 domain)

    // ---- Q B-frags from Qt [bh][d][s] (pre-scaled): lane = q column ----
    bf16x8 qf0, qf1;
    {
        const unsigned short* qb = Qt + (size_t)bh * HD * S_LEN + q0 + wave * 16 + l15;
        union { bf16x8 v; unsigned short u[8]; } u0, u1;
        #pragma unroll
        for (int j = 0; j < 8; ++j) {
            u0.u[j] = qb[(quad * 8 + j) * S_LEN];
            u1.u[j] = qb[(32 + quad * 8 + j) * S_LEN];
        }
        qf0 = u0.v; qf1 = u1.v;
    }

    f32x4 Z[4];
    #pragma unroll
    for (int i = 0; i < 4; ++i) Z[i] = (f32x4){0.f, 0.f, 0.f, 0.f};
    float rsum = 0.f;

    unsigned short* pw = Pl + wave * 1024;
    const int pwrow = l15 * 64;
    const int qthr  = wave * 16 + l15 - quad * 4;   // mask if n*16+r > qthr

    for (int kt = klo; kt <= khi; ++kt) {
        __syncthreads();
        #pragma unroll
        for (int i = 0; i < 2; ++i) {       // K tile [key][d]
            int c0 = (i * 4 + wave) * 64;
            int c  = c0 + lane;
            int r = c >> 3, pc = c & 7, q = pc ^ (r & 7);
            GLDS16(Kh + ((size_t)bh * S_LEN + kt * 64 + r) * HD + q * 8, Ks + c0 * 8);
        }
        #pragma unroll
        for (int i = 0; i < 2; ++i) {       // V tile [d][key]
            int c0 = (i * 4 + wave) * 64;
            int c  = c0 + lane;
            int d = c >> 3, pc = c & 7, q = pc ^ (d & 7);
            GLDS16(Vt + ((size_t)bh * HD + d) * S_LEN + kt * 64 + q * 8, Vs + c0 * 8);
        }
        __syncthreads();

        const bool diag = (kt == qt);
        const int nmax = diag ? wave : 3;

        // ---- S^T tiles: rows = keys, col = q. p = exp2(s - M0), pack to pw ----
        #pragma unroll
        for (int n = 0; n < 4; ++n) {
            int woff = pwrow + (((2 * n + (quad >> 1)) ^ (l15 & 7)) << 3) + (quad & 1) * 4;
            if (n <= nmax) {
                int rk = n * 16 + l15;       // A-operand: lane = key row
                int x = rk & 7;
                bf16x8 kv0 = *(const bf16x8*)(Ks + rk * 64 + ((quad    ) ^ x) * 8);
                bf16x8 kv1 = *(const bf16x8*)(Ks + rk * 64 + ((4 + quad) ^ x) * 8);
                f32x4 t4 = (f32x4){-M0, -M0, -M0, -M0};
                t4 = __builtin_amdgcn_mfma_f32_16x16x32_bf16(kv0, qf0, t4, 0, 0, 0);
                t4 = __builtin_amdgcn_mfma_f32_16x16x32_bf16(kv1, qf1, t4, 0, 0, 0);
                float p[4];
                #pragma unroll
                for (int r = 0; r < 4; ++r) {
                    p[r] = exp2f(t4[r]);
                    if (diag && (n * 16 + r) > qthr) p[r] = 0.f;
                    rsum += p[r];
                }
                uint2 pk;
                pk.x = pk_trunc(p[0], p[1]);
                pk.y = pk_trunc(p[2], p[3]);
                *(uint2*)(pw + woff) = pk;
            } else {
                *(uint2*)(pw + woff) = (uint2){0u, 0u};
            }
        }

        // ---- Z^T += V^T P ----
        const int khmax = diag ? (wave >> 1) : 1;
        for (int kh = 0; kh <= khmax; ++kh) {
            bf16x8 pa = *(const bf16x8*)(pw + pwrow + ((kh * 4 + quad) ^ (l15 & 7)) * 8);
            #pragma unroll
            for (int ni = 0; ni < 4; ++ni) {
                int rd = ni * 16 + l15;      // A-operand: lane = d row
                bf16x8 vb = *(const bf16x8*)(Vs + rd * 64 + ((kh * 4 + quad) ^ (rd & 7)) * 8);
                Z[ni] = __builtin_amdgcn_mfma_f32_16x16x32_bf16(vb, pa, Z[ni], 0, 0, 0);
            }
        }
    }

    // ---- combine quad partial sums (disjoint key subsets per quad) ----
    rsum += __shfl_xor(rsum, 16);
    rsum += __shfl_xor(rsum, 32);

    const int ql = wave * 16 + l15;          // q within 64-tile (lane = q column)
    if (part < 0) {
        const int b = bh >> 4, h = bh & (NH - 1);
        float inv = 1.f / rsum;
        size_t rowoff = (size_t)(b * S_LEN + q0 + ql) * DMODEL + h * HD;
        #pragma unroll
        for (int ni = 0; ni < 4; ++ni) {
            ushort4 o;
            o.x = f2bf(Z[ni][0] * inv);
            o.y = f2bf(Z[ni][1] * inv);
            o.z = f2bf(Z[ni][2] * inv);
            o.w = f2bf(Z[ni][3] * inv);
            *(ushort4*)(zb + rowoff + ni * 16 + quad * 4) = o;
        }
    } else {
        const int slot = (qt - 17) * 2 + part;
        float* zpo = Zp + ((size_t)(slot * 32 + bh) * 64) * 64;
        #pragma unroll
        for (int ni = 0; ni < 4; ++ni) {
            float4 st;
            st.x = Z[ni][0]; st.y = Z[ni][1]; st.z = Z[ni][2]; st.w = Z[ni][3];
            *(float4*)(zpo + (size_t)ql * 64 + ni * 16 + quad * 4) = st;
        }
        if (quad == 0)
            lp[(size_t)(slot * 32 + bh) * 64 + ql] = rsum;
    }
}

// ---------------------------------------------------------------------------
// Merge additive partials: zb = (Z0+Z1)/(l0+l1), grid (32 bh, 15 split qt)
// ---------------------------------------------------------------------------
__global__ __launch_bounds__(256) void attn_merge_kernel(
    const float* __restrict__ Zp, const float* __restrict__ lp,
    unsigned short* __restrict__ zb) {
    const int bh = blockIdx.x, qi = blockIdx.y, qt = 17 + qi;
    const int t = threadIdx.x;
    const int q = t >> 2;             // 0..63
    const int d0 = (t & 3) << 4;      // 0,16,32,48
    const int s0 = qi * 2, s1 = s0 + 1;
    float l = lp[(size_t)(s0 * 32 + bh) * 64 + q] +
              lp[(size_t)(s1 * 32 + bh) * 64 + q];
    float inv = 1.f / l;
    const float* z0 = Zp + ((size_t)(s0 * 32 + bh) * 64 + q) * 64 + d0;
    const float* z1 = Zp + ((size_t)(s1 * 32 + bh) * 64 + q) * 64 + d0;
    const int b = bh >> 4, h = bh & (NH - 1);
    unsigned short* o =
        zb + (size_t)(b * S_LEN + qt * 64 + q) * DMODEL + h * HD + d0;
    #pragma unroll
    for (int i = 0; i < 16; i += 4) {
        float4 a = *(const float4*)(z0 + i);
        float4 c = *(const float4*)(z1 + i);
        ushort4 ov;
        ov.x = f2bf((a.x + c.x) * inv);
        ov.y = f2bf((a.y + c.y) * inv);
        ov.z = f2bf((a.z + c.z) * inv);
        ov.w = f2bf((a.w + c.w) * inv);
        *(ushort4*)(o + i) = ov;
    }
}

// ---------------------------------------------------------------------------
extern "C" void kernel_launch(void* const* d_in, const int* in_sizes, int n_in,
                              void* d_out, int out_size, void* d_ws, size_t ws_size,
                              hipStream_t stream)
{
    const float* x     = (const float*)d_in[0];
    const float* w_qkv = (const float*)d_in[1];
    const float* b_qkv = (const float*)d_in[2];
    const float* w_out = (const float*)d_in[3];
    const float* b_out = (const float*)d_in[4];
    float* out = (float*)d_out;

    unsigned short* wsu   = (unsigned short*)d_ws;
    unsigned short* xb    = wsu;                       // 4096*1024
    unsigned short* wqkvT = xb    + (size_t)4194304;   // 3072*1024
    unsigned short* woutT = wqkvT + (size_t)3145728;   // 1024*1024
    unsigned short* Qt    = woutT + (size_t)1048576;   // 32*64*2048 (pre-scaled)
    unsigned short* Kh    = Qt    + (size_t)4194304;
    unsigned short* Vt    = Kh    + (size_t)4194304;
    unsigned short* zb    = Vt    + (size_t)4194304;   // 4096*1024
    float* Zp = (float*)(zb + (size_t)4194304);        // 30*32*64*64 fp32
    float* lp = Zp + (size_t)30 * 32 * 64 * 64;        // 30*32*64 fp32

    prep_kernel<<<dim3(8192), 256, 0, stream>>>(x, w_qkv, w_out, xb, wqkvT, woutT);

    gemm_qkv_kernel<<<dim3(768), 256, 0, stream>>>(
        xb, wqkvT, b_qkv, Qt, Kh, Vt);

    attn_mfma_kernel<<<dim3(2 * NH, 47), 256, 0, stream>>>(Qt, Kh, Vt, zb, Zp, lp);
    attn_merge_kernel<<<dim3(2 * NH, 15), 256, 0, stream>>>(Zp, lp, zb);

    gemm_out_kernel<<<dim3(512), 256, 0, stream>>>(
        zb, woutT, b_out, out);
}